// Round 2
// baseline (209.277 us; speedup 1.0000x reference)
//
#include <hip/hip_runtime.h>
#include <math.h>

// MoE router: logits = x[16384,2048] @ W^T[2048,64]; softmax; top-2; renorm.
//
// R8 post-mortem: depth-2 reg prefetch gained only 4us. Cause: __syncthreads
// emits s_waitcnt vmcnt(0) -> every step drains the YOUNGEST (t+2) loads, so
// the barrier serializes on fresh ~900cyc latency regardless of depth.
//
// R9: latency-tolerant schedule.
//  (a) K-loop barriers are raw s_barrier with COUNTED vmcnt: the x(t+2)
//      prefetch (2 youngest vm ops) stays in flight across the barrier;
//      only the W DMAs the next step needs are retired. Issue order pinned
//      with sched_barrier(0) so the count is exact.
//  (b) TPB=32, 256 thr (4 waves), grid 512 -> 2 blocks/CU (LDS 48KB+8.5KB):
//      independent barrier domains overlap each other's residual stalls.
//  (c) W staged via global_load_lds width=16 (linear dst, L2-resident src):
//      W never passes through VGPRs; vmcnt ledger = {W DMA x4, x loads x2}.
//
// Per-iteration vm ledger (per wave, pinned order):
//   1. DMA W(t+1) -> buf[(t+1)&1]        (4 ops)
//   2. load x(t+2) -> regs               (2 ops, if t+2<32)
//   3. compute(buf[t&1])                 (ds_reads; compiler lgkm waits)
//   4. stage_x x(t+1) -> buf[(t+1)&1]    (ds_writes; compiler waits vmcnt(6)->pxa)
//   5. s_waitcnt vmcnt(2) lgkmcnt(0)     (retires the 4 W DMAs; ds ops done)
//   6. s_barrier                         (x(t+2) still in flight!)
// WAR: step-1 DMA overwrites the buffer read in iter t-1; covered by iter
// t-1's step-5 lgkmcnt(0) + step-6 barrier. Last iter (t=30) has no x loads
// -> vmcnt(0) there so all 4 W DMAs retire.
//
// fp16 split-precision MFMA (verified R5/R6, absmax 0.002): x=xh+xl, W=wh+wl,
// logits = xh*wh + xl*wh + xh*wl, fp32 acc.
// Block: 32 tok x 64 exp x K2048; 4 waves = (nh,kh), each M32xN32xK32 per
// 64-k step. W pre-split+pre-swizzled into a 512KB image by w_split.
//
// LDS swizzle: tile rows x 8 granules (granule = 8 fp16 = 16B); slot (r,g)
// holds source granule g^(r&7). Frag read (row r, granule gs) reads slot
// gs^(r&7): 8 lanes/bank-group on b128 = conflict-free baseline.

typedef _Float16 half8  __attribute__((ext_vector_type(8)));
typedef float    floatx4 __attribute__((ext_vector_type(4)));

#define NTOK  16384
#define DDIM  2048
#define NE    64
#define TPB   32     // tokens per block
#define NSTEP 32     // K tiles of 64

__device__ inline void split8(const float4& a, const float4& b,
                              half8& hi, half8& lo) {
    float f[8] = {a.x, a.y, a.z, a.w, b.x, b.y, b.z, b.w};
#pragma unroll
    for (int j = 0; j < 8; ++j) {
        const _Float16 h = (_Float16)f[j];
        hi[j] = h;
        lo[j] = (_Float16)(f[j] - (float)h);
    }
}

typedef const __attribute__((address_space(1))) unsigned int* as1_u32p;
typedef __attribute__((address_space(3))) unsigned int*       as3_u32p;

__device__ inline void gload_lds16(const void* g, void* l) {
    // 16B per lane; LDS dst is wave-uniform base + lane*16 (linear), global
    // src is per-lane. Counts against vmcnt.
    __builtin_amdgcn_global_load_lds((as1_u32p)g, (as3_u32p)l, 16, 0, 0);
}

// ---- kernel 1: pre-split + pre-swizzle W into the staging image ----
// img granule idx = step*1024 + half*512 + e*8 + g ; contents =
// (hi|lo fp16 of) W[e][step*64 + 8*(g^(e&7)) .. +8]
__global__ __launch_bounds__(256) void w_split(const float* __restrict__ W,
                                               _Float16* __restrict__ img) {
    const int idx  = blockIdx.x * 256 + threadIdx.x;  // 0..32767
    const int step = idx >> 10;
    const int u    = idx & 1023;
    const int hl   = u >> 9;
    const int v    = u & 511;
    const int e    = v >> 3, g = v & 7;
    const float* src = W + (size_t)e * DDIM + step * 64 + 8 * (g ^ (e & 7));
    const float4 a = *(const float4*)(src);
    const float4 b = *(const float4*)(src + 4);
    half8 hi, lo;
    split8(a, b, hi, lo);
    *(half8*)(img + (size_t)idx * 8) = (hl == 0) ? hi : lo;
}

// ---- kernel 2: staged MFMA GEMM + softmax + top-2 ----
__global__ __launch_bounds__(256, 2) void router_mfma(
    const float* __restrict__ x,
    const _Float16* __restrict__ img,
    float* __restrict__ out)
{
    // buffer (12288 fp16 = 24KB): xh@0 (2048), xl@2048, wh@4096 (4096), wl@8192
    __shared__ __align__(16) _Float16 tiles[2 * 12288];   // 48KB double buffer
    __shared__ __align__(16) float lg[TPB * 68];          // logits slab, 68-pad

    const int tid = threadIdx.x;
    const int L   = tid & 63;
    const int wv  = __builtin_amdgcn_readfirstlane(tid >> 6);  // 0..3
    const int kh  = wv & 1;          // k half of the 64-k step
    const int nh  = wv >> 1;         // expert 32-half
    const int c   = L & 15, q = L >> 4;
    const int tok0 = blockIdx.x * TPB;

    // frag LDS offsets (fp16 elems); row&7 == c&7 for both A and B
    const int gfrag = (q + 4 * kh) ^ (L & 7);
    int aoff[2], boff[2];
#pragma unroll
    for (int mt = 0; mt < 2; ++mt)
        aoff[mt] = ((mt * 16 + c) * 8 + gfrag) * 8;
#pragma unroll
    for (int nt = 0; nt < 2; ++nt)
        boff[nt] = ((nh * 32 + nt * 16 + c) * 8 + gfrag) * 8;

    // x staging map: thread -> (row sr, slot-granule so); src granule so^(sr&7)
    const int sr = tid >> 3, so = tid & 7;   // 32 rows x 8 granules
    const float* xsrc = x + (size_t)(tok0 + sr) * DDIM + 8 * (so ^ (sr & 7));
    const int    xdst = (sr * 8 + so) * 8;   // fp16 elem offset in xh region

    floatx4 acc[2][2];
#pragma unroll
    for (int i = 0; i < 2; ++i)
#pragma unroll
        for (int j = 0; j < 2; ++j) acc[i][j] = (floatx4)0.f;

    // W DMA: 16KB/step, 4 waves x 4 rounds x (64 lanes x 16B)
    auto stage_w = [&](int sel, int t) {
        const char* src = (const char*)img + (size_t)t * 16384;
#pragma unroll
        for (int r = 0; r < 4; ++r) {
            const int gi0 = r * 256 + wv * 64;                 // wave-uniform
            gload_lds16(src + (size_t)(gi0 + L) * 16,
                        &tiles[sel * 12288 + 4096 + gi0 * 8]);
        }
    };

    auto stage_x = [&](int sel, const float4& xa, const float4& xb) {
        _Float16* nb = &tiles[sel * 12288];
        half8 hi, lo; split8(xa, xb, hi, lo);
        *(half8*)(nb + xdst)        = hi;
        *(half8*)(nb + 2048 + xdst) = lo;
    };

    auto compute = [&](int sel) {
        const _Float16* base = &tiles[sel * 12288];
        const _Float16* xh = base;
        const _Float16* xl = base + 2048;
        const _Float16* wh = base + 4096;
        const _Float16* wl = base + 8192;

        half8 Ah[2], Al[2], Bh[2], Bl[2];
#pragma unroll
        for (int mt = 0; mt < 2; ++mt) {
            Ah[mt] = *(const half8*)(xh + aoff[mt]);
            Al[mt] = *(const half8*)(xl + aoff[mt]);
        }
#pragma unroll
        for (int nt = 0; nt < 2; ++nt) {
            Bh[nt] = *(const half8*)(wh + boff[nt]);
            Bl[nt] = *(const half8*)(wl + boff[nt]);
        }
#pragma unroll
        for (int mt = 0; mt < 2; ++mt)
#pragma unroll
            for (int nt = 0; nt < 2; ++nt) {
                acc[mt][nt] = __builtin_amdgcn_mfma_f32_16x16x32_f16(Ah[mt], Bh[nt], acc[mt][nt], 0, 0, 0);
                acc[mt][nt] = __builtin_amdgcn_mfma_f32_16x16x32_f16(Al[mt], Bh[nt], acc[mt][nt], 0, 0, 0);
                acc[mt][nt] = __builtin_amdgcn_mfma_f32_16x16x32_f16(Ah[mt], Bl[nt], acc[mt][nt], 0, 0, 0);
            }
    };

    // ---- prologue: ledger [W0 x4, x0 x2, x1 x2] ----
    float4 pxa, pxb;
    {
        stage_w(0, 0);
        __builtin_amdgcn_sched_barrier(0);
        const float4 xa = *(const float4*)(xsrc);
        const float4 xb = *(const float4*)(xsrc + 4);
        __builtin_amdgcn_sched_barrier(0);
        pxa = *(const float4*)(xsrc + 64);
        pxb = *(const float4*)(xsrc + 68);
        __builtin_amdgcn_sched_barrier(0);
        stage_x(0, xa, xb);          // compiler waits vmcnt(2) -> W0+x0 retired
        asm volatile("s_waitcnt vmcnt(2) lgkmcnt(0)" ::: "memory");
        __builtin_amdgcn_sched_barrier(0);
        __builtin_amdgcn_s_barrier();
    }

    // ---- K loop: compute t, DMA W(t+1), stage x(t+1), prefetch x(t+2) ----
    for (int t = 0; t < NSTEP - 1; ++t) {
        stage_w((t + 1) & 1, t + 1);                    // 4 vm ops (oldest)
        __builtin_amdgcn_sched_barrier(0);
        float4 nxa = pxa, nxb = pxb;
        if (t + 2 < NSTEP) {                            // 2 vm ops (youngest)
            nxa = *(const float4*)(xsrc + (t + 2) * 64);
            nxb = *(const float4*)(xsrc + (t + 2) * 64 + 4);
        }
        __builtin_amdgcn_sched_barrier(0);
        compute(t & 1);
        stage_x((t + 1) & 1, pxa, pxb);
        if (t + 2 < NSTEP)
            asm volatile("s_waitcnt vmcnt(2) lgkmcnt(0)" ::: "memory");
        else
            asm volatile("s_waitcnt vmcnt(0) lgkmcnt(0)" ::: "memory");
        __builtin_amdgcn_sched_barrier(0);
        __builtin_amdgcn_s_barrier();
        pxa = nxa; pxb = nxb;
    }
    compute((NSTEP - 1) & 1);
    __syncthreads();   // full drain before exch aliases the tile buffers

    // ---- kh-pair reduction (exchange slab aliases the tile buffers) ----
    float* exch = (float*)tiles;
    const int p = nh;   // pair id for both kh
    if (kh == 1) {
        float* e0 = &exch[(p * 64 + L) * 20];
        *(float4*)(e0 + 0)  = make_float4(acc[0][0][0], acc[0][0][1], acc[0][0][2], acc[0][0][3]);
        *(float4*)(e0 + 4)  = make_float4(acc[0][1][0], acc[0][1][1], acc[0][1][2], acc[0][1][3]);
        *(float4*)(e0 + 8)  = make_float4(acc[1][0][0], acc[1][0][1], acc[1][0][2], acc[1][0][3]);
        *(float4*)(e0 + 12) = make_float4(acc[1][1][0], acc[1][1][1], acc[1][1][2], acc[1][1][3]);
    }
    __syncthreads();
    if (kh == 0) {
        const float* e0 = &exch[(p * 64 + L) * 20];
        float4 v;
        v = *(const float4*)(e0 + 0);  acc[0][0][0] += v.x; acc[0][0][1] += v.y; acc[0][0][2] += v.z; acc[0][0][3] += v.w;
        v = *(const float4*)(e0 + 4);  acc[0][1][0] += v.x; acc[0][1][1] += v.y; acc[0][1][2] += v.z; acc[0][1][3] += v.w;
        v = *(const float4*)(e0 + 8);  acc[1][0][0] += v.x; acc[1][0][1] += v.y; acc[1][0][2] += v.z; acc[1][0][3] += v.w;
        v = *(const float4*)(e0 + 12); acc[1][1][0] += v.x; acc[1][1][1] += v.y; acc[1][1][2] += v.z; acc[1][1][3] += v.w;
        // scatter: C/D layout col(n)=lane&15, row(m)=(lane>>4)*4+reg
#pragma unroll
        for (int mt = 0; mt < 2; ++mt)
#pragma unroll
            for (int nt = 0; nt < 2; ++nt)
#pragma unroll
                for (int r = 0; r < 4; ++r)
                    lg[(mt * 16 + q * 4 + r) * 68 + nh * 32 + nt * 16 + c] = acc[mt][nt][r];
    }
    __syncthreads();

    // ---- softmax + top-2: thread t < 32 owns token tok0+t ----
    if (tid < TPB) {
        const int token = tok0 + tid;
        float* row = &lg[tid * 68];
        float pr[NE];
#pragma unroll
        for (int e = 0; e < NE; ++e) pr[e] = row[e];

        float m = pr[0];
#pragma unroll
        for (int e = 1; e < NE; ++e) m = fmaxf(m, pr[e]);
        float s = 0.f;
#pragma unroll
        for (int e = 0; e < NE; ++e) { pr[e] = expf(pr[e] - m); s += pr[e]; }
        const float inv = 1.f / s;

        // lax.top_k tie-break = lowest index first -> strict '>' ascending scan
        float v1 = -1.f; int i1 = 0;
#pragma unroll
        for (int e = 0; e < NE; ++e) { if (pr[e] > v1) { v1 = pr[e]; i1 = e; } }
        float v2 = -1.f; int i2 = 0;
#pragma unroll
        for (int e = 0; e < NE; ++e) { if (e != i1 && pr[e] > v2) { v2 = pr[e]; i2 = e; } }

        const float ts = v1 + v2;
        float* out_tp = out;              // top_k_probs  [NTOK][2]
        float* out_ti = out + 2 * NTOK;   // top_k_indices[NTOK][2] (float values)
        *(float2*)(out_tp + token * 2) = make_float2(v1 / ts, v2 / ts);
        *(float2*)(out_ti + token * 2) = make_float2((float)i1, (float)i2);

#pragma unroll
        for (int e = 0; e < NE; ++e) row[e] = pr[e] * inv;
    }
    __syncthreads();

    // ---- cooperative coalesced probs write: 32 tok x 64 = 2048 floats ----
    {
        float* out_p = out + 4 * NTOK + (size_t)tok0 * NE;
#pragma unroll
        for (int i = 0; i < 2; ++i) {
            const int f = tid + 256 * i;        // float4 idx, 512 total
            const int r = f >> 4, c4 = f & 15;
            const float4 v = *(const float4*)&lg[r * 68 + 4 * c4];
            *(float4*)(out_p + f * 4) = v;
        }
    }
}

extern "C" void kernel_launch(void* const* d_in, const int* in_sizes, int n_in,
                              void* d_out, int out_size, void* d_ws, size_t ws_size,
                              hipStream_t stream) {
    const float* x = (const float*)d_in[0];
    const float* W = (const float*)d_in[1];
    float* out     = (float*)d_out;
    _Float16* img  = (_Float16*)d_ws;   // 512 KB pre-swizzled W image

    w_split<<<dim3(128), dim3(256), 0, stream>>>(W, img);
    router_mfma<<<dim3(NTOK / TPB), dim3(256), 0, stream>>>(x, img, out);
}